// Round 5
// baseline (662.673 us; speedup 1.0000x reference)
//
#include <hip/hip_runtime.h>

#define NN 32768
#define KK 16
#define DD 6
// State row per node-slot j: 256 B = h fp16[64] (natural) | c fp16[64] PERMUTED
// [lr][nt] (pos = (col&15)*4 + (col>>4)).  Row 0 = zero.
// Round-5 structure (ledger-driven):
//  * k0/WxF RESTORED (R4 fusion lost: random E gather +47 MB/depth >> 16.8 MB
//    sequential Wx stream).  k0 is the R1 LDS-free version (~22 us).
//  * kd gather is DIRECT-TO-REGISTER (R0 discipline): no LDS stage round-trip
//    in the per-k chain (R2/R3's ds_write->ds_read serialization cost ~15 us).
//    Per wave-k: 2x16B h loads (A-frag, 4-lane/row coalesced) + 4x8B permuted-c
//    loads = 6 VMEM insts / 64 lines.  Child ids preloaded (2xint4); C-layout
//    ids via 4 __shfl.  3-deep software pipeline (named reg sets, static idx).
//  * WRITE_SIZE unreliable on gfx950 (R3 falsification) -> steer by dur/FETCH.

typedef short short8 __attribute__((ext_vector_type(8)));
typedef float floatx4 __attribute__((ext_vector_type(4)));
typedef _Float16 half4v __attribute__((ext_vector_type(4)));
typedef _Float16 half8 __attribute__((ext_vector_type(8)));

__device__ __forceinline__ float sigm(float x) { return 1.0f / (1.0f + __expf(-x)); }
__device__ __forceinline__ float ftanh(float x) {
    float e = __expf(2.0f * x);
    return 1.0f - 2.0f / (e + 1.0f);
}
__device__ __forceinline__ unsigned short f2bf(float x) {   // RNE fp32->bf16
    union { float f; unsigned u; } v; v.f = x;
    unsigned r = v.u + 0x7FFF + ((v.u >> 16) & 1);
    return (unsigned short)(r >> 16);
}
__device__ __forceinline__ float bf2f(unsigned short h) {
    union { unsigned u; float f; } v; v.u = ((unsigned)h) << 16; return v.f;
}

// ---------------------------------------------------------------------------
// K_PREP: build global B-fragments once.  32768 values total, 1 per thread.
//   WwF: 16 nt x 2 ks x 64 ln x 8  bf16   (W_w,  256 cols)
//   BiF: 12 nt x 2 ks x 64 ln x 8  bf16   (U_iuo, 192 cols)
//   BfF:  4 nt x 2 ks x 64 ln x 8  fp16   (U_f,    64 cols)
__global__ __launch_bounds__(256) void k_prep(
    const float* __restrict__ W_w, const float* __restrict__ U_iuo,
    const float* __restrict__ U_f,
    unsigned short* __restrict__ WwF, unsigned short* __restrict__ BiF,
    _Float16* __restrict__ BfF)
{
    const int t = blockIdx.x * 256 + threadIdx.x;      // 0..32767
    if (t < 16384) {
        const int u = t, j = u & 7, ln = (u >> 3) & 63, ks = (u >> 9) & 1, nt = u >> 10;
        const int col = nt * 16 + (ln & 15), k = ks * 32 + (ln >> 4) * 8 + j;
        WwF[u] = f2bf(W_w[k * 256 + col]);
    } else if (t < 28672) {
        const int u = t - 16384, j = u & 7, ln = (u >> 3) & 63, ks = (u >> 9) & 1, nt = u >> 10;
        const int col = nt * 16 + (ln & 15), k = ks * 32 + (ln >> 4) * 8 + j;
        BiF[u] = f2bf(U_iuo[k * 192 + col]);
    } else {
        const int u = t - 28672, j = u & 7, ln = (u >> 3) & 63, ks = (u >> 9) & 1, nt = u >> 10;
        const int col = nt * 16 + (ln & 15), k = ks * 32 + (ln >> 4) * 8 + j;
        BfF[u] = (_Float16)U_f[k * 64 + col];
    }
}

// ---------------------------------------------------------------------------
// K0_ALL: LDS-free, barrier-free.  A-frags converted in-register from direct
// E row loads; B-frags from the L2-hot WwF table.
__global__ __launch_bounds__(256) void k0_all(
    const int* __restrict__ labels, const float* __restrict__ E,
    const unsigned short* __restrict__ WwF, const float* __restrict__ W_b,
    _Float16* __restrict__ WxF)
{
    const int tid = threadIdx.x;
    const int blk = blockIdx.x & 511;
    const int dep = blockIdx.x >> 9;
    const int n0 = blk * 64;
    const int ln = tid & 63, wv = tid >> 6;
    const int lr = ln & 15, qd = ln >> 4;
    const int lab = labels[(size_t)dep * NN + n0 + wv * 16 + lr];
    const float4* __restrict__ e4 = (const float4*)(E + (size_t)lab * 64);
    short8 af[2];
#pragma unroll
    for (int ks = 0; ks < 2; ++ks) {
        const float4 v0 = e4[ks * 8 + qd * 2 + 0];
        const float4 v1 = e4[ks * 8 + qd * 2 + 1];
        short8 a;
        a[0] = (short)f2bf(v0.x); a[1] = (short)f2bf(v0.y);
        a[2] = (short)f2bf(v0.z); a[3] = (short)f2bf(v0.w);
        a[4] = (short)f2bf(v1.x); a[5] = (short)f2bf(v1.y);
        a[6] = (short)f2bf(v1.z); a[7] = (short)f2bf(v1.w);
        af[ks] = a;
    }
    const short8* __restrict__ bw = (const short8*)WwF;
    _Float16* __restrict__ base =
        WxF + ((size_t)(dep * 512 + blk) * 4 + wv) * 16 * 256 + (size_t)ln * 4;
#pragma unroll
    for (int nt = 0; nt < 16; ++nt) {
        floatx4 a = (floatx4){0.f, 0.f, 0.f, 0.f};
        a = __builtin_amdgcn_mfma_f32_16x16x32_bf16(af[0], bw[(nt * 2 + 0) * 64 + ln], a, 0, 0, 0);
        a = __builtin_amdgcn_mfma_f32_16x16x32_bf16(af[1], bw[(nt * 2 + 1) * 64 + ln], a, 0, 0, 0);
        const float bb = W_b[nt * 16 + lr];
        half4v hv;
#pragma unroll
        for (int r = 0; r < 4; ++r) hv[r] = (_Float16)(a[r] + bb);
        *(half4v*)&base[nt * 256] = hv;
    }
}

// ---------------------------------------------------------------------------
// KD: block = 32 nodes, 4 waves.  wave wv: group g=wv&1 (16 nodes), k-half
// kh=wv>>1 (children kh*8..+8).  Direct-register gather, 3-deep pipeline.
__global__ __launch_bounds__(256, 3) void kd_fused(
    const int* __restrict__ cidx, const _Float16* __restrict__ sprev,
    const _Float16* __restrict__ Wx, const unsigned short* __restrict__ BiF,
    const _Float16* __restrict__ BfF, _Float16* __restrict__ snext,
    float* __restrict__ out, int first, int last)
{
    __shared__ __align__(16) _Float16 BfL[4096];       // [4 nt][2 ks][64 ln][8]
    __shared__ float comb[2][2][1088];                 // [g][hs|bf][ln*17+..]
    const int tid = threadIdx.x;
    {   // stage U_f frags: 512 half8, 2 per thread
        const half8* __restrict__ src = (const half8*)BfF;
        half8* dst = (half8*)BfL;
        dst[tid] = src[tid];
        dst[tid + 256] = src[tid + 256];
    }
    const int ln = tid & 63, wv = tid >> 6;
    const int g = wv & 1, kh = wv >> 1;
    const int lr = ln & 15, qd = ln >> 4;
    const int n0 = blockIdx.x * 32;
    const _Float16* __restrict__ wbase =
        Wx + ((size_t)(blockIdx.x >> 1) * 4 + (blockIdx.x & 1) * 2 + g) * 4096 + (size_t)ln * 4;
    __syncthreads();                                   // BfL ready

    float hsA[2][8];
    float bfv[4][4];
#pragma unroll
    for (int ks = 0; ks < 2; ++ks)
#pragma unroll
        for (int j = 0; j < 8; ++j) hsA[ks][j] = 0.f;
#pragma unroll
    for (int r = 0; r < 4; ++r)
#pragma unroll
        for (int nt = 0; nt < 4; ++nt) bfv[r][nt] = 0.f;

    if (!first) {
        float wfx[4][4];
#pragma unroll
        for (int nt = 0; nt < 4; ++nt) {               // f tiles 0..3 (C-layout)
            const half4v fv = *(const half4v*)&wbase[nt * 256];
#pragma unroll
            for (int r = 0; r < 4; ++r) wfx[r][nt] = (float)fv[r];
        }
        const half8* __restrict__ bl = (const half8*)BfL;
        // this lane's A-row node = lr; its 8 child ids are 32 B contiguous
        const int4 iv0 = *(const int4*)&cidx[(size_t)(n0 + g * 16 + lr) * KK + kh * 8];
        const int4 iv1 = *(const int4*)&cidx[(size_t)(n0 + g * 16 + lr) * KK + kh * 8 + 4];

        int icA[4], icB[4], icC[4];
        half8 hA0, hA1, hB0, hB1, hC0, hC1;
        half4v cA[4], cB[4], cC[4];

#define IDS(ic, idv) {                                                  \
        _Pragma("unroll") for (int r = 0; r < 4; ++r)                   \
            ic[r] = __shfl((idv), qd * 4 + r, 64); }
#define GL(h0, h1, cc, idv, ic) {                                       \
        const _Float16* rp_ = sprev + (size_t)(idv) * 128;              \
        h0 = *(const half8*)(rp_ + qd * 8);                             \
        h1 = *(const half8*)(rp_ + 32 + qd * 8);                        \
        _Pragma("unroll") for (int r = 0; r < 4; ++r)                   \
            cc[r] = *(const half4v*)(sprev + (size_t)ic[r] * 128 + 64 + lr * 4); }
#define BODY(h0, h1, cc) {                                              \
        _Pragma("unroll") for (int nt = 0; nt < 4; ++nt) {              \
            floatx4 gg = (floatx4){0.f, 0.f, 0.f, 0.f};                 \
            gg = __builtin_amdgcn_mfma_f32_16x16x32_f16(h0, bl[(nt * 2 + 0) * 64 + ln], gg, 0, 0, 0); \
            gg = __builtin_amdgcn_mfma_f32_16x16x32_f16(h1, bl[(nt * 2 + 1) * 64 + ln], gg, 0, 0, 0); \
            _Pragma("unroll") for (int r = 0; r < 4; ++r)               \
                bfv[r][nt] = fmaf(sigm(wfx[r][nt] + gg[r]), (float)cc[r][nt], bfv[r][nt]); \
        }                                                               \
        _Pragma("unroll") for (int j = 0; j < 8; ++j) {                 \
            hsA[0][j] += (float)h0[j]; hsA[1][j] += (float)h1[j]; } }

        // 3-deep pipeline: each GL has two full BODYs of latency cover.
        IDS(icA, iv0.x); GL(hA0, hA1, cA, iv0.x, icA);
        IDS(icB, iv0.y); GL(hB0, hB1, cB, iv0.y, icB);
        IDS(icC, iv0.z); GL(hC0, hC1, cC, iv0.z, icC);
        BODY(hA0, hA1, cA); IDS(icA, iv0.w); GL(hA0, hA1, cA, iv0.w, icA);
        BODY(hB0, hB1, cB); IDS(icB, iv1.x); GL(hB0, hB1, cB, iv1.x, icB);
        BODY(hC0, hC1, cC); IDS(icC, iv1.y); GL(hC0, hC1, cC, iv1.y, icC);
        BODY(hA0, hA1, cA); IDS(icA, iv1.z); GL(hA0, hA1, cA, iv1.z, icA);
        BODY(hB0, hB1, cB); IDS(icB, iv1.w); GL(hB0, hB1, cB, iv1.w, icB);
        BODY(hC0, hC1, cC);
        BODY(hA0, hA1, cA);
        BODY(hB0, hB1, cB);
#undef IDS
#undef GL
#undef BODY

        // ---- combine k-halves across wave pairs
        __syncthreads();
        if (kh == 1) {
#pragma unroll
            for (int ks = 0; ks < 2; ++ks)
#pragma unroll
                for (int j = 0; j < 8; ++j) comb[g][0][ln * 17 + ks * 8 + j] = hsA[ks][j];
#pragma unroll
            for (int r = 0; r < 4; ++r)
#pragma unroll
                for (int nt = 0; nt < 4; ++nt) comb[g][1][ln * 17 + r * 4 + nt] = bfv[r][nt];
        }
        __syncthreads();
        if (kh == 0) {
#pragma unroll
            for (int ks = 0; ks < 2; ++ks)
#pragma unroll
                for (int j = 0; j < 8; ++j) hsA[ks][j] += comb[g][0][ln * 17 + ks * 8 + j];
#pragma unroll
            for (int r = 0; r < 4; ++r)
#pragma unroll
                for (int nt = 0; nt < 4; ++nt) bfv[r][nt] += comb[g][1][ln * 17 + r * 4 + nt];
        }
    }
    if (kh == 0) {
        // ---- iuo GEMM: in-register split-bf16 hsum @ U_iuo, 12 out-tiles
        floatx4 acc[12];
#pragma unroll
        for (int nt = 0; nt < 12; ++nt) acc[nt] = (floatx4){0.f, 0.f, 0.f, 0.f};
        if (!first) {
            short8 ahi[2], alo[2];
#pragma unroll
            for (int ks = 0; ks < 2; ++ks)
#pragma unroll
                for (int j = 0; j < 8; ++j) {
                    const float v = hsA[ks][j];
                    const unsigned short hi = f2bf(v);
                    ahi[ks][j] = (short)hi;
                    alo[ks][j] = (short)f2bf(v - bf2f(hi));
                }
            const short8* __restrict__ bi = (const short8*)BiF;
#pragma unroll
            for (int nt = 0; nt < 12; ++nt) {
                floatx4 a = (floatx4){0.f, 0.f, 0.f, 0.f};
#pragma unroll
                for (int ks = 0; ks < 2; ++ks) {
                    const short8 bu = bi[(nt * 2 + ks) * 64 + ln];
                    a = __builtin_amdgcn_mfma_f32_16x16x32_bf16(alo[ks], bu, a, 0, 0, 0);
                    a = __builtin_amdgcn_mfma_f32_16x16x32_bf16(ahi[ks], bu, a, 0, 0, 0);
                }
                acc[nt] = a;
            }
        }
        // ---- gate epilogue (direct stores; R2-proven fastest epilogue)
#pragma unroll
        for (int nt = 0; nt < 4; ++nt) {
            const half4v iv = *(const half4v*)&wbase[(4 + nt) * 256];
            const half4v uv = *(const half4v*)&wbase[(8 + nt) * 256];
            const half4v ov = *(const half4v*)&wbase[(12 + nt) * 256];
#pragma unroll
            for (int r = 0; r < 4; ++r) {
                const int node = n0 + g * 16 + qd * 4 + r;
                const float ig = sigm(acc[nt][r] + (float)iv[r]);
                const float ug = ftanh(acc[4 + nt][r] + (float)uv[r]);
                const float og = sigm(acc[8 + nt][r] + (float)ov[r]);
                const float nc = fmaf(ig, ug, bfv[r][nt]);
                const float nh = og * ftanh(nc);
                if (last) {
                    out[(size_t)node * 64 + nt * 16 + lr] = nh;
                } else {
                    snext[(size_t)(node + 1) * 128 + nt * 16 + lr] = (_Float16)nh;      // h natural
                    snext[(size_t)(node + 1) * 128 + 64 + lr * 4 + nt] = (_Float16)nc;  // c permuted
                }
            }
        }
    }
    if (!last && blockIdx.x == 0 && tid < 64)
        ((unsigned*)snext)[tid] = 0u;                  // zero init-state row
}

extern "C" void kernel_launch(void* const* d_in, const int* in_sizes, int n_in,
                              void* d_out, int out_size, void* d_ws, size_t ws_size,
                              hipStream_t stream)
{
    const int*   labels = (const int*)d_in[0];    // [6, 32768]
    const int*   child  = (const int*)d_in[1];    // [6, 32768, 16]
    const float* E      = (const float*)d_in[2];  // [100000, 64]
    const float* W_w    = (const float*)d_in[3];  // [64, 256]
    const float* W_b    = (const float*)d_in[4];  // [256]
    const float* U_f    = (const float*)d_in[5];  // [64, 64]
    const float* U_iuo  = (const float*)d_in[6];  // [64, 192]
    float* out = (float*)d_out;

    // ws: s0,s1 = (NN+1)*256 B state ping-pong (8.4 MB each);
    //     WxF = 6 x NN*256 fp16 frags (100.7 MB); then WwF/BiF/BfF tables (64 KB).
    _Float16* s0 = (_Float16*)d_ws;
    _Float16* s1 = s0 + (size_t)(NN + 1) * 128;
    _Float16* WxF = s1 + (size_t)(NN + 1) * 128;
    unsigned short* WwF = (unsigned short*)(WxF + (size_t)6 * NN * 256);
    unsigned short* BiF = WwF + 16384;
    _Float16* BfF = (_Float16*)(BiF + 12288);

    k_prep<<<128, 256, 0, stream>>>(W_w, U_iuo, U_f, WwF, BiF, BfF);
    k0_all<<<6 * (NN / 64), 256, 0, stream>>>(labels, E, WwF, W_b, WxF);

    _Float16* sp = s0;
    _Float16* sn = s1;
    for (int d = 0; d < DD; ++d) {
        const int last = (d == DD - 1);
        kd_fused<<<NN / 32, 256, 0, stream>>>(
            child + (size_t)d * NN * KK, sp,
            WxF + (size_t)d * NN * 256,
            BiF, BfF, sn, out, d == 0, last);
        _Float16* ts = sp; sp = sn; sn = ts;
    }
}

// Round 6
// 332.255 us; speedup vs baseline: 1.9945x; 1.9945x over previous
//
#include <hip/hip_runtime.h>

#define NN 32768
#define KK 16
#define DD 6
// State row per node-slot j (R0 format, proven 47us/4.3TB/s raw gather):
//   u32 words  [j*96 .. j*96+64):        hg = (int16)(h*32767) | (int16)(g*2048)<<16
//   f16 halves [j*192+128 .. j*192+192): c as fp16
// Row 0 = all zero.
// Ledger: R0's per-lane scalar gather (32 small loads/lane/k, no LDS/MFMA/shfl
// in the per-k chain) is the only structure that ran the gather fabric at
// ~4.3 TB/s raw; all "wider/fewer inst" rewrites (R1/R2/R5) lost MLP and
// regressed.  R6 = R0 kd verbatim + (a) children split 8/8 across wave pairs
// (grid 512->1024, 8->16 gather-waves/CU; combine once off critical path),
// (b) global bf16 frag tables replace 26KB Bi/Bf LDS staging, (c) R1's
// LDS-free k0 (~22us vs 45).  WRITE_SIZE unreliable on gfx950 (R3).

typedef short short8 __attribute__((ext_vector_type(8)));
typedef float floatx4 __attribute__((ext_vector_type(4)));
typedef _Float16 half4v __attribute__((ext_vector_type(4)));

__device__ __forceinline__ float sigm(float x) { return 1.0f / (1.0f + __expf(-x)); }
__device__ __forceinline__ float ftanh(float x) {
    float e = __expf(2.0f * x);
    return 1.0f - 2.0f / (e + 1.0f);
}
__device__ __forceinline__ unsigned short f2bf(float x) {   // RNE fp32->bf16
    union { float f; unsigned u; } v; v.f = x;
    unsigned r = v.u + 0x7FFF + ((v.u >> 16) & 1);
    return (unsigned short)(r >> 16);
}
__device__ __forceinline__ float bf2f(unsigned short h) {
    union { unsigned u; float f; } v; v.u = ((unsigned)h) << 16; return v.f;
}

// ---------------------------------------------------------------------------
// K_PREP: global B-frag tables, all bf16.  32768 values, 1 per thread.
//   WwF: 16 nt x 2 ks x 64 ln x 8   (W_w,  256 cols)
//   BiF: 12 nt x 2 ks x 64 ln x 8   (U_iuo, 192 cols)
//   UfF:  4 nt x 2 ks x 64 ln x 8   (U_f,    64 cols)
__global__ __launch_bounds__(256) void k_prep(
    const float* __restrict__ W_w, const float* __restrict__ U_iuo,
    const float* __restrict__ U_f,
    unsigned short* __restrict__ WwF, unsigned short* __restrict__ BiF,
    unsigned short* __restrict__ UfF)
{
    const int t = blockIdx.x * 256 + threadIdx.x;      // 0..32767
    if (t < 16384) {
        const int u = t, j = u & 7, ln = (u >> 3) & 63, ks = (u >> 9) & 1, nt = u >> 10;
        const int col = nt * 16 + (ln & 15), k = ks * 32 + (ln >> 4) * 8 + j;
        WwF[u] = f2bf(W_w[k * 256 + col]);
    } else if (t < 28672) {
        const int u = t - 16384, j = u & 7, ln = (u >> 3) & 63, ks = (u >> 9) & 1, nt = u >> 10;
        const int col = nt * 16 + (ln & 15), k = ks * 32 + (ln >> 4) * 8 + j;
        BiF[u] = f2bf(U_iuo[k * 192 + col]);
    } else {
        const int u = t - 28672, j = u & 7, ln = (u >> 3) & 63, ks = (u >> 9) & 1, nt = u >> 10;
        const int col = nt * 16 + (ln & 15), k = ks * 32 + (ln >> 4) * 8 + j;
        UfF[u] = f2bf(U_f[k * 64 + col]);
    }
}

// ---------------------------------------------------------------------------
// K0_ALL: LDS-free, barrier-free (R1-proven ~22us).  A-frags converted
// in-register from direct E row loads; B-frags from the L2-hot WwF table.
__global__ __launch_bounds__(256) void k0_all(
    const int* __restrict__ labels, const float* __restrict__ E,
    const unsigned short* __restrict__ WwF, const float* __restrict__ W_b,
    _Float16* __restrict__ WxF)
{
    const int tid = threadIdx.x;
    const int blk = blockIdx.x & 511;
    const int dep = blockIdx.x >> 9;
    const int n0 = blk * 64;
    const int ln = tid & 63, wv = tid >> 6;
    const int lr = ln & 15, qd = ln >> 4;
    const int lab = labels[(size_t)dep * NN + n0 + wv * 16 + lr];
    const float4* __restrict__ e4 = (const float4*)(E + (size_t)lab * 64);
    short8 af[2];
#pragma unroll
    for (int ks = 0; ks < 2; ++ks) {
        const float4 v0 = e4[ks * 8 + qd * 2 + 0];
        const float4 v1 = e4[ks * 8 + qd * 2 + 1];
        short8 a;
        a[0] = (short)f2bf(v0.x); a[1] = (short)f2bf(v0.y);
        a[2] = (short)f2bf(v0.z); a[3] = (short)f2bf(v0.w);
        a[4] = (short)f2bf(v1.x); a[5] = (short)f2bf(v1.y);
        a[6] = (short)f2bf(v1.z); a[7] = (short)f2bf(v1.w);
        af[ks] = a;
    }
    const short8* __restrict__ bw = (const short8*)WwF;
    _Float16* __restrict__ base =
        WxF + ((size_t)(dep * 512 + blk) * 4 + wv) * 16 * 256 + (size_t)ln * 4;
#pragma unroll
    for (int nt = 0; nt < 16; ++nt) {
        floatx4 a = (floatx4){0.f, 0.f, 0.f, 0.f};
        a = __builtin_amdgcn_mfma_f32_16x16x32_bf16(af[0], bw[(nt * 2 + 0) * 64 + ln], a, 0, 0, 0);
        a = __builtin_amdgcn_mfma_f32_16x16x32_bf16(af[1], bw[(nt * 2 + 1) * 64 + ln], a, 0, 0, 0);
        const float bb = W_b[nt * 16 + lr];
        half4v hv;
#pragma unroll
        for (int r = 0; r < 4; ++r) hv[r] = (_Float16)(a[r] + bb);
        *(half4v*)&base[nt * 256] = hv;
    }
}

// ---------------------------------------------------------------------------
// KD: block = 32 nodes, 4 waves.  wave wv: group g=wv&1 (16 nodes), k-half
// kh=wv>>1 (children kh*8..+8).  Gather loop = R0 verbatim (per-lane C-layout
// scalar loads, 1-deep id prefetch, zero LDS/shfl/MFMA in the chain).
__global__ __launch_bounds__(256, 4) void kd_fused(
    const int* __restrict__ cidx, const unsigned* __restrict__ sprev,
    const _Float16* __restrict__ Wx, const unsigned short* __restrict__ BiF,
    const unsigned short* __restrict__ UfF, unsigned* __restrict__ snext,
    float* __restrict__ out, int first, int last)
{
    __shared__ __align__(16) float comb[2][2176];      // per group: 64 ln x 34 f32
    const int tid = threadIdx.x;
    const int ln = tid & 63, wv = tid >> 6;
    const int g = wv & 1, kh = wv >> 1;
    const int lr = ln & 15, qd = ln >> 4;
    const int n0 = blockIdx.x * 32;
    const _Float16* __restrict__ wbase =
        Wx + ((size_t)(blockIdx.x * 2 + g)) * 4096 + (size_t)ln * 4;

    float hs[4][4] = {{0.f}}, bfv[4][4] = {{0.f}};
    float wfx[4][4];
#pragma unroll
    for (int nt = 0; nt < 4; ++nt) {                   // f tiles 0..3 (C-layout)
        const half4v fv = *(const half4v*)&wbase[nt * 256];
#pragma unroll
        for (int r = 0; r < 4; ++r) wfx[r][nt] = (float)fv[r];
    }

    if (!first) {
        // ---- R0 gather loop (verbatim), over this wave's 8-child half
        const _Float16* __restrict__ ch = (const _Float16*)sprev;
        const size_t cb = (size_t)(n0 + g * 16 + qd * 4) * KK + kh * 8;
        int id[4];
#pragma unroll
        for (int r = 0; r < 4; ++r) id[r] = cidx[cb + r * KK];
#pragma unroll 1
        for (int k = 0; k < 8; ++k) {
            unsigned hg[4][4];
            _Float16 cv[4][4];
#pragma unroll
            for (int r = 0; r < 4; ++r)
#pragma unroll
                for (int nt = 0; nt < 4; ++nt)
                    hg[r][nt] = sprev[(size_t)id[r] * 96 + nt * 16 + lr];
#pragma unroll
            for (int r = 0; r < 4; ++r)
#pragma unroll
                for (int nt = 0; nt < 4; ++nt)
                    cv[r][nt] = ch[(size_t)id[r] * 192 + 128 + nt * 16 + lr];
            int idn[4];
            if (k + 1 < 8) {                           // prefetch ids k+1
#pragma unroll
                for (int r = 0; r < 4; ++r) idn[r] = cidx[cb + r * KK + k + 1];
            }
#pragma unroll
            for (int r = 0; r < 4; ++r)
#pragma unroll
                for (int nt = 0; nt < 4; ++nt) {
                    const float h = (float)(short)(hg[r][nt] & 0xFFFFu) * (1.f / 32767.f);
                    const float gg = (float)((int)hg[r][nt] >> 16) * (1.f / 2048.f);
                    hs[r][nt] += h;
                    bfv[r][nt] = fmaf(sigm(wfx[r][nt] + gg), (float)cv[r][nt], bfv[r][nt]);
                }
            if (k + 1 < 8) {
#pragma unroll
                for (int r = 0; r < 4; ++r) id[r] = idn[r];
            }
        }
        // ---- combine k-halves across the wave pair (once, off critical path)
        __syncthreads();
        if (kh == 1) {
            float* const pb = &comb[g][ln * 34];
#pragma unroll
            for (int r = 0; r < 4; ++r)
#pragma unroll
                for (int nt = 0; nt < 4; ++nt) {
                    pb[r * 4 + nt] = hs[r][nt];
                    pb[16 + r * 4 + nt] = bfv[r][nt];
                }
        }
        __syncthreads();
        if (kh == 0) {
            const float* const pb = &comb[g][ln * 34];
#pragma unroll
            for (int r = 0; r < 4; ++r)
#pragma unroll
                for (int nt = 0; nt < 4; ++nt) {
                    hs[r][nt] += pb[r * 4 + nt];
                    bfv[r][nt] += pb[16 + r * 4 + nt];
                }
        }
    }
    if (kh != 0) return;

    // ---- hsum -> group-private LDS A-tile, split hi/lo bf16 (R0 scheme;
    //      same-wave ds_write->ds_read needs no barrier)
    unsigned short* const ah_t = (unsigned short*)comb[g];        // Ah[16][68]
    unsigned short* const al_t = ah_t + 16 * 68;                  // Al[16][68]
#pragma unroll
    for (int r = 0; r < 4; ++r)
#pragma unroll
        for (int nt = 0; nt < 4; ++nt) {
            const int m = qd * 4 + r, col = nt * 16 + lr;
            const unsigned short hi = f2bf(hs[r][nt]);
            ah_t[m * 68 + col] = hi;
            al_t[m * 68 + col] = f2bf(hs[r][nt] - bf2f(hi));
        }
    short8 ah[2], al[2];
#pragma unroll
    for (int ks = 0; ks < 2; ++ks) {
        ah[ks] = *(const short8*)&ah_t[lr * 68 + ks * 32 + qd * 8];
        al[ks] = *(const short8*)&al_t[lr * 68 + ks * 32 + qd * 8];
    }
    // ---- iuo GEMM: split-bf16 hsum @ U_iuo, global BiF frags, 12 out-tiles
    const short8* __restrict__ bi = (const short8*)BiF;
    floatx4 acc[12];
#pragma unroll
    for (int nt = 0; nt < 12; ++nt) {
        floatx4 a = (floatx4){0.f, 0.f, 0.f, 0.f};
#pragma unroll
        for (int ks = 0; ks < 2; ++ks) {
            const short8 bu = bi[(nt * 2 + ks) * 64 + ln];
            a = __builtin_amdgcn_mfma_f32_16x16x32_bf16(al[ks], bu, a, 0, 0, 0);
            a = __builtin_amdgcn_mfma_f32_16x16x32_bf16(ah[ks], bu, a, 0, 0, 0);
        }
        acc[nt] = a;
    }
    // ---- gate epilogue (R0 numerics)
    float nhv[4][4], ncv[4][4];
#pragma unroll
    for (int nt = 0; nt < 4; ++nt) {
        const int col = nt * 16 + lr;
        const half4v iv = *(const half4v*)&wbase[(4 + nt) * 256];
        const half4v uv = *(const half4v*)&wbase[(8 + nt) * 256];
        const half4v ov = *(const half4v*)&wbase[(12 + nt) * 256];
#pragma unroll
        for (int r = 0; r < 4; ++r) {
            const int node = n0 + g * 16 + qd * 4 + r;
            const float ig = sigm(acc[nt][r] + (float)iv[r]);
            const float ug = ftanh(acc[4 + nt][r] + (float)uv[r]);
            const float og = sigm(acc[8 + nt][r] + (float)ov[r]);
            const float nc = fmaf(ig, ug, bfv[r][nt]);
            const float nh = og * ftanh(nc);
            nhv[nt][r] = nh;
            ncv[nt][r] = nc;
            if (last) {
                out[(size_t)node * 64 + col] = nh;
            } else {
                al_t[(qd * 4 + r) * 68 + col] = f2bf(nh);   // Al dead: restage nh
            }
        }
    }
    if (!last) {
        // ---- g = nh @ U_f (global UfF frags; same-wave LDS dep via lgkmcnt)
        short8 ag[2];
#pragma unroll
        for (int ks = 0; ks < 2; ++ks)
            ag[ks] = *(const short8*)&al_t[lr * 68 + ks * 32 + qd * 8];
        const short8* __restrict__ bf = (const short8*)UfF;
        floatx4 gacc[4];
#pragma unroll
        for (int nt = 0; nt < 4; ++nt) {
            gacc[nt] = (floatx4){0.f, 0.f, 0.f, 0.f};
#pragma unroll
            for (int ks = 0; ks < 2; ++ks) {
                const short8 bfr = bf[(nt * 2 + ks) * 64 + ln];
                gacc[nt] = __builtin_amdgcn_mfma_f32_16x16x32_bf16(ag[ks], bfr, gacc[nt], 0, 0, 0);
            }
        }
        _Float16* dh = (_Float16*)snext;
#pragma unroll
        for (int nt = 0; nt < 4; ++nt) {
#pragma unroll
            for (int r = 0; r < 4; ++r) {
                const int node = n0 + g * 16 + qd * 4 + r;
                // |nh|<1, |g|<=8 -> int16 scales safe (R0-proven)
                const int hq = (int)rintf(nhv[nt][r] * 32767.f);
                const int gq = (int)rintf(gacc[nt][r] * 2048.f);
                snext[(size_t)(node + 1) * 96 + nt * 16 + lr] =
                    ((unsigned)hq & 0xFFFFu) | ((unsigned)gq << 16);
                dh[(size_t)(node + 1) * 192 + 128 + nt * 16 + lr] =
                    (_Float16)ncv[nt][r];
            }
        }
        if (blockIdx.x == 0 && tid < 96)
            snext[tid] = 0u;                           // zero init-state row
    }
}

extern "C" void kernel_launch(void* const* d_in, const int* in_sizes, int n_in,
                              void* d_out, int out_size, void* d_ws, size_t ws_size,
                              hipStream_t stream)
{
    const int*   labels = (const int*)d_in[0];    // [6, 32768]
    const int*   child  = (const int*)d_in[1];    // [6, 32768, 16]
    const float* E      = (const float*)d_in[2];  // [100000, 64]
    const float* W_w    = (const float*)d_in[3];  // [64, 256]
    const float* W_b    = (const float*)d_in[4];  // [256]
    const float* U_f    = (const float*)d_in[5];  // [64, 64]
    const float* U_iuo  = (const float*)d_in[6];  // [64, 192]
    float* out = (float*)d_out;

    // ws: s0,s1 = (NN+1)*384 B state ping-pong (12.6 MB each);
    //     WxF = 6 x NN*256 fp16 frags (100.7 MB); then frag tables (64 KB).
    unsigned* s0 = (unsigned*)d_ws;
    unsigned* s1 = s0 + (size_t)(NN + 1) * 96;
    _Float16* WxF = (_Float16*)(s1 + (size_t)(NN + 1) * 96);
    unsigned short* WwF = (unsigned short*)(WxF + (size_t)6 * NN * 256);
    unsigned short* BiF = WwF + 16384;
    unsigned short* UfF = BiF + 12288;

    k_prep<<<128, 256, 0, stream>>>(W_w, U_iuo, U_f, WwF, BiF, UfF);
    k0_all<<<6 * (NN / 64), 256, 0, stream>>>(labels, E, WwF, W_b, WxF);

    unsigned* sp = s0;
    unsigned* sn = s1;
    for (int d = 0; d < DD; ++d) {
        const int last = (d == DD - 1);
        kd_fused<<<NN / 32, 256, 0, stream>>>(
            child + (size_t)d * NN * KK, sp,
            WxF + (size_t)d * NN * 256,
            BiF, UfF, sn, out, d == 0, last);
        unsigned* ts = sp; sp = sn; sn = ts;
    }
}